// Round 1
// baseline (1113.593 us; speedup 1.0000x reference)
//
#include <hip/hip_runtime.h>
#include <hip/hip_bf16.h>

#define N_NODES 65536
#define N_EDGES 1048576
#define D_FEAT  64

// ---------------- workspace layout (bytes) ----------------
// counts   : N int      @ 0          (256 KB)
// dinv     : N float    @ 0x040000   (256 KB)
// offsets  : N int      @ 0x080000   (256 KB)
// cursor   : N int      @ 0x0C0000   (256 KB)
// blockSums: 256 int    @ 0x100000
// blockOffs: 256 int    @ 0x100400
// csr_src  : E int      @ 0x200000   (4 MB)
// csr_norm : E float    @ 0x600000   (4 MB)
// h0       : N*64 float @ 0xA00000   (16 MB)
// h1       : N*64 float @ 0x1A00000  (16 MB)
// total ~42 MB

__global__ void count_deg(const int* __restrict__ dst, int* __restrict__ counts) {
    int e = blockIdx.x * blockDim.x + threadIdx.x;
    if (e < N_EDGES) atomicAdd(&counts[dst[e]], 1);
}

__global__ void compute_dinv(const int* __restrict__ counts, float* __restrict__ dinv) {
    int v = blockIdx.x * blockDim.x + threadIdx.x;
    if (v < N_NODES) dinv[v] = rsqrtf((float)(counts[v] + 1));  // +1 self-loop
}

// exclusive scan of counts, 256 blocks x 256 threads
__global__ void scan_pass1(const int* __restrict__ counts, int* __restrict__ offsets,
                           int* __restrict__ blockSums) {
    __shared__ int sdata[256];
    int tid = threadIdx.x;
    int gid = blockIdx.x * 256 + tid;
    int v = counts[gid];
    sdata[tid] = v;
    __syncthreads();
    for (int off = 1; off < 256; off <<= 1) {
        int t = (tid >= off) ? sdata[tid - off] : 0;
        __syncthreads();
        sdata[tid] += t;
        __syncthreads();
    }
    offsets[gid] = sdata[tid] - v;  // exclusive
    if (tid == 255) blockSums[blockIdx.x] = sdata[255];
}

__global__ void scan_pass2(int* __restrict__ blockSums, int* __restrict__ blockOffs) {
    __shared__ int sdata[256];
    int tid = threadIdx.x;
    int v = blockSums[tid];
    sdata[tid] = v;
    __syncthreads();
    for (int off = 1; off < 256; off <<= 1) {
        int t = (tid >= off) ? sdata[tid - off] : 0;
        __syncthreads();
        sdata[tid] += t;
        __syncthreads();
    }
    blockOffs[tid] = sdata[tid] - v;
}

__global__ void scan_pass3(int* __restrict__ offsets, const int* __restrict__ blockOffs,
                           int* __restrict__ cursor) {
    int gid = blockIdx.x * 256 + threadIdx.x;
    int o = offsets[gid] + blockOffs[blockIdx.x];
    offsets[gid] = o;
    cursor[gid] = o;
}

__global__ void scatter_edges(const int* __restrict__ src, const int* __restrict__ dst,
                              const float* __restrict__ dinv, int* __restrict__ cursor,
                              int* __restrict__ csr_src, float* __restrict__ csr_norm) {
    int e = blockIdx.x * blockDim.x + threadIdx.x;
    if (e >= N_EDGES) return;
    int s = src[e];
    int d = dst[e];
    int pos = atomicAdd(&cursor[d], 1);
    csr_src[pos] = s;
    csr_norm[pos] = dinv[s] * dinv[d];
}

// hidden = temp[9] * x   (vectorized float4)
__global__ void init_hidden(const float* __restrict__ x, const float* __restrict__ temp,
                            float* __restrict__ hidden) {
    int i = blockIdx.x * blockDim.x + threadIdx.x;  // float4 index
    float tk = temp[9];
    float4 v = ((const float4*)x)[i];
    v.x *= tk; v.y *= tk; v.z *= tk; v.w *= tk;
    ((float4*)hidden)[i] = v;
}

// one wave per destination node, lane = feature. No atomics.
__global__ void hop_kernel(const float* __restrict__ h_in, float* __restrict__ h_out,
                           float* __restrict__ hidden, const float* __restrict__ temp,
                           const int* __restrict__ offsets, const int* __restrict__ counts,
                           const int* __restrict__ csr_src, const float* __restrict__ csr_norm,
                           const float* __restrict__ dinv, int k) {
    int gtid = blockIdx.x * blockDim.x + threadIdx.x;
    int v = gtid >> 6;        // node = wave index
    int lane = gtid & 63;     // feature = lane
    float dv = dinv[v];
    float acc = dv * dv * h_in[v * D_FEAT + lane];   // self-loop term
    int start = offsets[v];
    int cnt = counts[v];
    for (int i = 0; i < cnt; ++i) {
        int s = csr_src[start + i];
        float w = csr_norm[start + i];
        acc += w * h_in[s * D_FEAT + lane];
    }
    h_out[v * D_FEAT + lane] = acc;
    hidden[v * D_FEAT + lane] += temp[k] * acc;
}

extern "C" void kernel_launch(void* const* d_in, const int* in_sizes, int n_in,
                              void* d_out, int out_size, void* d_ws, size_t ws_size,
                              hipStream_t stream) {
    const float* x    = (const float*)d_in[0];
    const float* temp = (const float*)d_in[1];
    const int*   ei   = (const int*)d_in[2];
    const int* src = ei;             // edge_index[0]
    const int* dst = ei + N_EDGES;   // edge_index[1]
    float* hidden = (float*)d_out;

    char* ws = (char*)d_ws;
    int*   counts    = (int*)  (ws + 0x000000);
    float* dinv      = (float*)(ws + 0x040000);
    int*   offsets   = (int*)  (ws + 0x080000);
    int*   cursor    = (int*)  (ws + 0x0C0000);
    int*   blockSums = (int*)  (ws + 0x100000);
    int*   blockOffs = (int*)  (ws + 0x100400);
    int*   csr_src   = (int*)  (ws + 0x200000);
    float* csr_norm  = (float*)(ws + 0x600000);
    float* h0        = (float*)(ws + 0xA00000);
    float* h1        = (float*)(ws + 0x1A00000);

    hipMemsetAsync(counts, 0, N_NODES * sizeof(int), stream);

    count_deg<<<N_EDGES / 256, 256, 0, stream>>>(dst, counts);
    compute_dinv<<<N_NODES / 256, 256, 0, stream>>>(counts, dinv);
    scan_pass1<<<256, 256, 0, stream>>>(counts, offsets, blockSums);
    scan_pass2<<<1, 256, 0, stream>>>(blockSums, blockOffs);
    scan_pass3<<<256, 256, 0, stream>>>(offsets, blockOffs, cursor);
    scatter_edges<<<N_EDGES / 256, 256, 0, stream>>>(src, dst, dinv, cursor, csr_src, csr_norm);

    init_hidden<<<(N_NODES * D_FEAT / 4) / 256, 256, 0, stream>>>(x, temp, hidden);

    // 9 hops: m=1..9, coefficient temp[9-m]; first hop reads x directly
    const int hop_blocks = (N_NODES * D_FEAT) / 256;  // 1 wave per node, 4 waves/block
    const float* hin = x;
    float* bufs[2] = {h0, h1};
    for (int m = 1; m <= 9; ++m) {
        float* hout = bufs[(m - 1) & 1];
        hop_kernel<<<hop_blocks, 256, 0, stream>>>(hin, hout, hidden, temp,
                                                   offsets, counts, csr_src, csr_norm,
                                                   dinv, 9 - m);
        hin = hout;
    }
}

// Round 2
// 570.149 us; speedup vs baseline: 1.9532x; 1.9532x over previous
//
#include <hip/hip_runtime.h>
#include <hip/hip_bf16.h>

#define N_NODES 65536
#define N_EDGES 1048576
#define D_FEAT  64

// ---------------- workspace layout (bytes) ----------------
// counts   : N int      @ 0          (256 KB)
// dinv     : N float    @ 0x040000   (256 KB)
// offsets  : N int      @ 0x080000   (256 KB)
// cursor   : N int      @ 0x0C0000   (256 KB)
// blockSums: 256 int    @ 0x100000
// blockOffs: 256 int    @ 0x100400
// csr      : E int2     @ 0x200000   (8 MB)  -- (src, norm-bits) interleaved
// h0       : N*64 float @ 0xA00000   (16 MB)
// h1       : N*64 float @ 0x1A00000  (16 MB)

__global__ void count_deg(const int* __restrict__ dst, int* __restrict__ counts) {
    int e = blockIdx.x * blockDim.x + threadIdx.x;
    if (e < N_EDGES) atomicAdd(&counts[dst[e]], 1);
}

__global__ void compute_dinv(const int* __restrict__ counts, float* __restrict__ dinv) {
    int v = blockIdx.x * blockDim.x + threadIdx.x;
    if (v < N_NODES) dinv[v] = rsqrtf((float)(counts[v] + 1));  // +1 self-loop
}

// exclusive scan of counts, 256 blocks x 256 threads
__global__ void scan_pass1(const int* __restrict__ counts, int* __restrict__ offsets,
                           int* __restrict__ blockSums) {
    __shared__ int sdata[256];
    int tid = threadIdx.x;
    int gid = blockIdx.x * 256 + tid;
    int v = counts[gid];
    sdata[tid] = v;
    __syncthreads();
    for (int off = 1; off < 256; off <<= 1) {
        int t = (tid >= off) ? sdata[tid - off] : 0;
        __syncthreads();
        sdata[tid] += t;
        __syncthreads();
    }
    offsets[gid] = sdata[tid] - v;  // exclusive
    if (tid == 255) blockSums[blockIdx.x] = sdata[255];
}

__global__ void scan_pass2(int* __restrict__ blockSums, int* __restrict__ blockOffs) {
    __shared__ int sdata[256];
    int tid = threadIdx.x;
    int v = blockSums[tid];
    sdata[tid] = v;
    __syncthreads();
    for (int off = 1; off < 256; off <<= 1) {
        int t = (tid >= off) ? sdata[tid - off] : 0;
        __syncthreads();
        sdata[tid] += t;
        __syncthreads();
    }
    blockOffs[tid] = sdata[tid] - v;
}

__global__ void scan_pass3(int* __restrict__ offsets, const int* __restrict__ blockOffs,
                           int* __restrict__ cursor) {
    int gid = blockIdx.x * 256 + threadIdx.x;
    int o = offsets[gid] + blockOffs[blockIdx.x];
    offsets[gid] = o;
    cursor[gid] = o;
}

__global__ void scatter_edges(const int* __restrict__ src, const int* __restrict__ dst,
                              const float* __restrict__ dinv, int* __restrict__ cursor,
                              int2* __restrict__ csr) {
    int e = blockIdx.x * blockDim.x + threadIdx.x;
    if (e >= N_EDGES) return;
    int s = src[e];
    int d = dst[e];
    int pos = atomicAdd(&cursor[d], 1);
    float w = dinv[s] * dinv[d];
    csr[pos] = make_int2(s, __float_as_int(w));
}

// hidden = temp[9] * x   (vectorized float4)
__global__ void init_hidden(const float* __restrict__ x, const float* __restrict__ temp,
                            float* __restrict__ hidden) {
    int i = blockIdx.x * blockDim.x + threadIdx.x;  // float4 index
    float tk = temp[9];
    float4 v = ((const float4*)x)[i];
    v.x *= tk; v.y *= tk; v.z *= tk; v.w *= tk;
    ((float4*)hidden)[i] = v;
}

// One wave per destination node, lane = feature. Wave-cooperative edge staging:
// each lane loads one (src,norm) int2 for up to 64 edges, broadcast via __shfl,
// 8 independent gathers in flight per round. Chunk padded to multiple of 8 with
// (src=v, w=0) dummies -- no remainder loop, no atomics.
__global__ void __launch_bounds__(256) hop_kernel(
        const float* __restrict__ h_in, float* __restrict__ h_out,
        float* __restrict__ hidden, const float* __restrict__ temp,
        const int* __restrict__ offsets, const int* __restrict__ counts,
        const int2* __restrict__ csr, const float* __restrict__ dinv, int k) {
    int gtid = blockIdx.x * blockDim.x + threadIdx.x;
    int v = gtid >> 6;        // node = wave index
    int lane = gtid & 63;     // feature = lane
    float dv = dinv[v];
    float acc = dv * dv * h_in[v * D_FEAT + lane];   // self-loop term
    int start = offsets[v];
    int cnt = counts[v];

    int i = 0;
    while (i < cnt) {
        int chunk = cnt - i;
        if (chunk > 64) chunk = 64;
        int2 e = make_int2(v, 0);              // dummy: gathers own row, weight 0
        if (lane < chunk) e = csr[start + i + lane];
        int rounds = (chunk + 7) >> 3;
        for (int r = 0; r < rounds; ++r) {
            int j = r * 8;
            int s0 = __shfl(e.x, j + 0), s1 = __shfl(e.x, j + 1);
            int s2 = __shfl(e.x, j + 2), s3 = __shfl(e.x, j + 3);
            int s4 = __shfl(e.x, j + 4), s5 = __shfl(e.x, j + 5);
            int s6 = __shfl(e.x, j + 6), s7 = __shfl(e.x, j + 7);
            float f0 = h_in[s0 * D_FEAT + lane];
            float f1 = h_in[s1 * D_FEAT + lane];
            float f2 = h_in[s2 * D_FEAT + lane];
            float f3 = h_in[s3 * D_FEAT + lane];
            float f4 = h_in[s4 * D_FEAT + lane];
            float f5 = h_in[s5 * D_FEAT + lane];
            float f6 = h_in[s6 * D_FEAT + lane];
            float f7 = h_in[s7 * D_FEAT + lane];
            float w0 = __int_as_float(__shfl(e.y, j + 0));
            float w1 = __int_as_float(__shfl(e.y, j + 1));
            float w2 = __int_as_float(__shfl(e.y, j + 2));
            float w3 = __int_as_float(__shfl(e.y, j + 3));
            float w4 = __int_as_float(__shfl(e.y, j + 4));
            float w5 = __int_as_float(__shfl(e.y, j + 5));
            float w6 = __int_as_float(__shfl(e.y, j + 6));
            float w7 = __int_as_float(__shfl(e.y, j + 7));
            acc += w0 * f0; acc += w1 * f1; acc += w2 * f2; acc += w3 * f3;
            acc += w4 * f4; acc += w5 * f5; acc += w6 * f6; acc += w7 * f7;
        }
        i += chunk;
    }

    h_out[v * D_FEAT + lane] = acc;
    hidden[v * D_FEAT + lane] += temp[k] * acc;
}

extern "C" void kernel_launch(void* const* d_in, const int* in_sizes, int n_in,
                              void* d_out, int out_size, void* d_ws, size_t ws_size,
                              hipStream_t stream) {
    const float* x    = (const float*)d_in[0];
    const float* temp = (const float*)d_in[1];
    const int*   ei   = (const int*)d_in[2];
    const int* src = ei;             // edge_index[0]
    const int* dst = ei + N_EDGES;   // edge_index[1]
    float* hidden = (float*)d_out;

    char* ws = (char*)d_ws;
    int*   counts    = (int*)  (ws + 0x000000);
    float* dinv      = (float*)(ws + 0x040000);
    int*   offsets   = (int*)  (ws + 0x080000);
    int*   cursor    = (int*)  (ws + 0x0C0000);
    int*   blockSums = (int*)  (ws + 0x100000);
    int*   blockOffs = (int*)  (ws + 0x100400);
    int2*  csr       = (int2*) (ws + 0x200000);
    float* h0        = (float*)(ws + 0xA00000);
    float* h1        = (float*)(ws + 0x1A00000);

    hipMemsetAsync(counts, 0, N_NODES * sizeof(int), stream);

    count_deg<<<N_EDGES / 256, 256, 0, stream>>>(dst, counts);
    compute_dinv<<<N_NODES / 256, 256, 0, stream>>>(counts, dinv);
    scan_pass1<<<256, 256, 0, stream>>>(counts, offsets, blockSums);
    scan_pass2<<<1, 256, 0, stream>>>(blockSums, blockOffs);
    scan_pass3<<<256, 256, 0, stream>>>(offsets, blockOffs, cursor);
    scatter_edges<<<N_EDGES / 256, 256, 0, stream>>>(src, dst, dinv, cursor, csr);

    init_hidden<<<(N_NODES * D_FEAT / 4) / 256, 256, 0, stream>>>(x, temp, hidden);

    // 9 hops: m=1..9, coefficient temp[9-m]; first hop reads x directly
    const int hop_blocks = (N_NODES * D_FEAT) / 256;  // 1 wave per node, 4 waves/block
    const float* hin = x;
    float* bufs[2] = {h0, h1};
    for (int m = 1; m <= 9; ++m) {
        float* hout = bufs[(m - 1) & 1];
        hop_kernel<<<hop_blocks, 256, 0, stream>>>(hin, hout, hidden, temp,
                                                   offsets, counts, csr, dinv, 9 - m);
        hin = hout;
    }
}

// Round 3
// 526.825 us; speedup vs baseline: 2.1138x; 1.0822x over previous
//
#include <hip/hip_runtime.h>
#include <hip/hip_bf16.h>

#define N_NODES 65536
#define N_EDGES 1048576
#define D_FEAT  64

// ---------------- workspace layout (bytes) ----------------
// counts   : N int      @ 0x000000   (256 KB)
// dinv     : N float    @ 0x040000   (256 KB)
// offsets  : N int      @ 0x080000   (256 KB)
// blockSums: 256 int    @ 0x0C0000
// blockOffs: 256 int    @ 0x0C0400
// csr      : E int2     @ 0x1FFF00   (8 MB, ends 0x9FFF00; [0x9FFF00,0xA00000) is
//                                     zeroed slack so uniform over-reads are safe)
// h0       : N*64 float @ 0xA00000   (16 MB)
// h1       : N*64 float @ 0x1A00000  (16 MB)
// rank     : E int      — ALIASES h1 (consumed by scatter before hop2 writes h1)

__global__ void count_deg(const int* __restrict__ dst, int* __restrict__ counts,
                          int* __restrict__ rank) {
    int e = blockIdx.x * blockDim.x + threadIdx.x;
    if (e < N_EDGES) rank[e] = atomicAdd(&counts[dst[e]], 1);
}

__global__ void compute_dinv(const int* __restrict__ counts, float* __restrict__ dinv) {
    int v = blockIdx.x * blockDim.x + threadIdx.x;
    if (v < N_NODES) dinv[v] = rsqrtf((float)(counts[v] + 1));  // +1 self-loop
}

// exclusive scan of counts, 256 blocks x 256 threads
__global__ void scan_pass1(const int* __restrict__ counts, int* __restrict__ offsets,
                           int* __restrict__ blockSums) {
    __shared__ int sdata[256];
    int tid = threadIdx.x;
    int gid = blockIdx.x * 256 + tid;
    int v = counts[gid];
    sdata[tid] = v;
    __syncthreads();
    for (int off = 1; off < 256; off <<= 1) {
        int t = (tid >= off) ? sdata[tid - off] : 0;
        __syncthreads();
        sdata[tid] += t;
        __syncthreads();
    }
    offsets[gid] = sdata[tid] - v;  // exclusive
    if (tid == 255) blockSums[blockIdx.x] = sdata[255];
}

__global__ void scan_pass2(int* __restrict__ blockSums, int* __restrict__ blockOffs) {
    __shared__ int sdata[256];
    int tid = threadIdx.x;
    int v = blockSums[tid];
    sdata[tid] = v;
    __syncthreads();
    for (int off = 1; off < 256; off <<= 1) {
        int t = (tid >= off) ? sdata[tid - off] : 0;
        __syncthreads();
        sdata[tid] += t;
        __syncthreads();
    }
    blockOffs[tid] = sdata[tid] - v;
}

__global__ void scan_pass3(int* __restrict__ offsets, const int* __restrict__ blockOffs) {
    int gid = blockIdx.x * 256 + threadIdx.x;
    offsets[gid] += blockOffs[blockIdx.x];
}

// No atomic: position = offsets[d] + rank[e] (rank recorded during count_deg)
__global__ void scatter_edges(const int* __restrict__ src, const int* __restrict__ dst,
                              const int* __restrict__ rank, const int* __restrict__ offsets,
                              const float* __restrict__ dinv, int2* __restrict__ csr) {
    int e = blockIdx.x * blockDim.x + threadIdx.x;
    if (e >= N_EDGES) return;
    int s = src[e];
    int d = dst[e];
    int pos = offsets[d] + rank[e];
    float w = dinv[s] * dinv[d];
    csr[pos] = make_int2(s, __float_as_int(w));
}

// Horner hop: g_out = sc * (A_hat @ g_in) + temp[k] * x
// One wave per node, lane = feature. Edge records fetched on the SCALAR pipe
// (node id is wave-uniform via readfirstlane -> s_load), weights feed
// v_fmac with an SGPR operand. 8 independent gathers in flight per round.
// Remainder: uniform weight-select to 0; CSR has 256B zeroed slack for over-reads.
__global__ void __launch_bounds__(256) hop_kernel(
        const float* __restrict__ g_in, const float* __restrict__ x,
        float* __restrict__ g_out, const float* __restrict__ temp,
        const int* __restrict__ offsets, const int* __restrict__ counts,
        const int2* __restrict__ csr, const float* __restrict__ dinv, int k) {
    int gtid = blockIdx.x * blockDim.x + threadIdx.x;
    int v = __builtin_amdgcn_readfirstlane(gtid >> 6);  // node, wave-uniform SGPR
    int lane = gtid & 63;                               // feature = lane

    float dv = dinv[v];
    int start = offsets[v];
    int cnt = counts[v];
    float tk = temp[k];
    float sc = (k == 1) ? temp[0] : 1.0f;  // first hop: g_in is unscaled x

    float acc = dv * dv * g_in[v * D_FEAT + lane];  // self-loop

    int rounds = (cnt + 7) >> 3;
    for (int r = 0; r < rounds; ++r) {
        int base = start + r * 8;
        int idx0 = r * 8;
        // uniform-address loads -> scalar pipe
        int2 e0 = csr[base + 0];
        int2 e1 = csr[base + 1];
        int2 e2 = csr[base + 2];
        int2 e3 = csr[base + 3];
        int2 e4 = csr[base + 4];
        int2 e5 = csr[base + 5];
        int2 e6 = csr[base + 6];
        int2 e7 = csr[base + 7];
        float f0 = g_in[e0.x * D_FEAT + lane];
        float f1 = g_in[e1.x * D_FEAT + lane];
        float f2 = g_in[e2.x * D_FEAT + lane];
        float f3 = g_in[e3.x * D_FEAT + lane];
        float f4 = g_in[e4.x * D_FEAT + lane];
        float f5 = g_in[e5.x * D_FEAT + lane];
        float f6 = g_in[e6.x * D_FEAT + lane];
        float f7 = g_in[e7.x * D_FEAT + lane];
        float w0 = (idx0 + 0 < cnt) ? __int_as_float(e0.y) : 0.0f;
        float w1 = (idx0 + 1 < cnt) ? __int_as_float(e1.y) : 0.0f;
        float w2 = (idx0 + 2 < cnt) ? __int_as_float(e2.y) : 0.0f;
        float w3 = (idx0 + 3 < cnt) ? __int_as_float(e3.y) : 0.0f;
        float w4 = (idx0 + 4 < cnt) ? __int_as_float(e4.y) : 0.0f;
        float w5 = (idx0 + 5 < cnt) ? __int_as_float(e5.y) : 0.0f;
        float w6 = (idx0 + 6 < cnt) ? __int_as_float(e6.y) : 0.0f;
        float w7 = (idx0 + 7 < cnt) ? __int_as_float(e7.y) : 0.0f;
        acc += w0 * f0; acc += w1 * f1; acc += w2 * f2; acc += w3 * f3;
        acc += w4 * f4; acc += w5 * f5; acc += w6 * f6; acc += w7 * f7;
    }

    g_out[v * D_FEAT + lane] = sc * acc + tk * x[v * D_FEAT + lane];
}

extern "C" void kernel_launch(void* const* d_in, const int* in_sizes, int n_in,
                              void* d_out, int out_size, void* d_ws, size_t ws_size,
                              hipStream_t stream) {
    const float* x    = (const float*)d_in[0];
    const float* temp = (const float*)d_in[1];
    const int*   ei   = (const int*)d_in[2];
    const int* src = ei;             // edge_index[0]
    const int* dst = ei + N_EDGES;   // edge_index[1]
    float* out = (float*)d_out;

    char* ws = (char*)d_ws;
    int*   counts    = (int*)  (ws + 0x000000);
    float* dinv      = (float*)(ws + 0x040000);
    int*   offsets   = (int*)  (ws + 0x080000);
    int*   blockSums = (int*)  (ws + 0x0C0000);
    int*   blockOffs = (int*)  (ws + 0x0C0400);
    int2*  csr       = (int2*) (ws + 0x1FFF00);   // ends 0x9FFF00
    char*  slack     =         (ws + 0x9FFF00);   // 256 B zeroed
    float* h0        = (float*)(ws + 0xA00000);
    float* h1        = (float*)(ws + 0x1A00000);
    int*   rank      = (int*)  h1;                // aliases h1, consumed pre-hop2

    hipMemsetAsync(counts, 0, N_NODES * sizeof(int), stream);
    hipMemsetAsync(slack, 0, 256, stream);

    count_deg<<<N_EDGES / 256, 256, 0, stream>>>(dst, counts, rank);
    compute_dinv<<<N_NODES / 256, 256, 0, stream>>>(counts, dinv);
    scan_pass1<<<256, 256, 0, stream>>>(counts, offsets, blockSums);
    scan_pass2<<<1, 256, 0, stream>>>(blockSums, blockOffs);
    scan_pass3<<<256, 256, 0, stream>>>(offsets, blockOffs);
    scatter_edges<<<N_EDGES / 256, 256, 0, stream>>>(src, dst, rank, offsets, dinv, csr);

    // Horner: p = temp[0]*x; for k=1..9: p = A_hat*p + temp[k]*x  (scale fused in hop1)
    const int hop_blocks = (N_NODES * D_FEAT) / 256;  // 1 wave per node
    const float* gin = x;
    float* bufs[2] = {h0, h1};
    for (int k = 1; k <= 9; ++k) {
        float* gout = (k == 9) ? out : bufs[(k - 1) & 1];
        hop_kernel<<<hop_blocks, 256, 0, stream>>>(gin, x, gout, temp,
                                                   offsets, counts, csr, dinv, k);
        gin = gout;
    }
}

// Round 4
// 520.024 us; speedup vs baseline: 2.1414x; 1.0131x over previous
//
#include <hip/hip_runtime.h>
#include <hip/hip_bf16.h>

#define N_NODES 65536
#define N_EDGES 1048576
#define D_FEAT  64

// ---------------- workspace layout (bytes) ----------------
// counts   : N int      @ 0x000000   (256 KB)
// dinv     : N float    @ 0x040000   (256 KB)
// offsets  : N int      @ 0x080000   (256 KB)
// blockSums: 256 int    @ 0x0C0000
// blockOffs: 256 int    @ 0x0C0400
// csr      : E int2     @ 0x1FFF00   (8 MB, ends 0x9FFF00; [0x9FFF00,0xA00000) is
//                                     zeroed slack so padded over-reads are safe)
// h0       : N*64 float @ 0xA00000   (16 MB)
// h1       : N*64 float @ 0x1A00000  (16 MB)
// rank     : E int      — ALIASES h1 (consumed by scatter before hop2 writes h1)

__global__ void count_deg(const int* __restrict__ dst, int* __restrict__ counts,
                          int* __restrict__ rank) {
    int e = blockIdx.x * blockDim.x + threadIdx.x;
    if (e < N_EDGES) rank[e] = atomicAdd(&counts[dst[e]], 1);
}

__global__ void compute_dinv(const int* __restrict__ counts, float* __restrict__ dinv) {
    int v = blockIdx.x * blockDim.x + threadIdx.x;
    if (v < N_NODES) dinv[v] = rsqrtf((float)(counts[v] + 1));  // +1 self-loop
}

// exclusive scan of counts, 256 blocks x 256 threads
__global__ void scan_pass1(const int* __restrict__ counts, int* __restrict__ offsets,
                           int* __restrict__ blockSums) {
    __shared__ int sdata[256];
    int tid = threadIdx.x;
    int gid = blockIdx.x * 256 + tid;
    int v = counts[gid];
    sdata[tid] = v;
    __syncthreads();
    for (int off = 1; off < 256; off <<= 1) {
        int t = (tid >= off) ? sdata[tid - off] : 0;
        __syncthreads();
        sdata[tid] += t;
        __syncthreads();
    }
    offsets[gid] = sdata[tid] - v;  // exclusive
    if (tid == 255) blockSums[blockIdx.x] = sdata[255];
}

__global__ void scan_pass2(int* __restrict__ blockSums, int* __restrict__ blockOffs) {
    __shared__ int sdata[256];
    int tid = threadIdx.x;
    int v = blockSums[tid];
    sdata[tid] = v;
    __syncthreads();
    for (int off = 1; off < 256; off <<= 1) {
        int t = (tid >= off) ? sdata[tid - off] : 0;
        __syncthreads();
        sdata[tid] += t;
        __syncthreads();
    }
    blockOffs[tid] = sdata[tid] - v;
}

__global__ void scan_pass3(int* __restrict__ offsets, const int* __restrict__ blockOffs) {
    int gid = blockIdx.x * 256 + threadIdx.x;
    offsets[gid] += blockOffs[blockIdx.x];
}

// No atomic: position = offsets[d] + rank[e] (rank recorded during count_deg)
__global__ void scatter_edges(const int* __restrict__ src, const int* __restrict__ dst,
                              const int* __restrict__ rank, const int* __restrict__ offsets,
                              const float* __restrict__ dinv, int2* __restrict__ csr) {
    int e = blockIdx.x * blockDim.x + threadIdx.x;
    if (e >= N_EDGES) return;
    int s = src[e];
    int d = dst[e];
    int pos = offsets[d] + rank[e];
    float w = dinv[s] * dinv[d];
    csr[pos] = make_int2(s, __float_as_int(w));
}

// Horner hop: g_out = sc * (A_hat @ g_in) + temp[k] * x
// One wave per node. PAIR-GATHER: lane holds float2 feature pair (2*(lane&31)),
// lower half-wave (lanes 0-31) gathers even edges' rows, upper half odd edges'.
// One global_load_dwordx2 covers TWO edges -> 2x bytes in flight per tracked
// request, 16 edges per round with 8 requests outstanding. Halves combined via
// __shfl_xor(32) at the end. Edge records fetched on the scalar pipe (node id
// wave-uniform). Padding: weight forced to 0 for slots >= cnt; csr has zeroed
// slack so over-reads at the global end are safe (pad slots read a valid/zero
// src and gather a row that is simply ignored).
__global__ void __launch_bounds__(256) hop_kernel(
        const float* __restrict__ g_in, const float* __restrict__ x,
        float* __restrict__ g_out, const float* __restrict__ temp,
        const int* __restrict__ offsets, const int* __restrict__ counts,
        const int2* __restrict__ csr, const float* __restrict__ dinv, int k) {
    int gtid = blockIdx.x * blockDim.x + threadIdx.x;
    int v = __builtin_amdgcn_readfirstlane(gtid >> 6);  // node, wave-uniform SGPR
    int lane = gtid & 63;
    int half = lane >> 5;          // 0: even edges, 1: odd edges
    int pairlane = lane & 31;      // feature-pair index (features 2p, 2p+1)

    float dv = dinv[v];
    int start = offsets[v];
    int cnt = counts[v];
    float tk = temp[k];
    float sc = (k == 1) ? temp[0] : 1.0f;  // first hop: g_in is unscaled x

    const float2* gin2 = (const float2*)g_in;
    float accx = 0.0f, accy = 0.0f;

    int rounds = (cnt + 15) >> 4;
    for (int r = 0; r < rounds; ++r) {
        int base = start + r * 16;
        int idx0 = r * 16;
        #pragma unroll
        for (int u = 0; u < 8; ++u) {
            int2 eA = csr[base + 2 * u];       // wave-uniform -> scalar loads
            int2 eB = csr[base + 2 * u + 1];
            int s = half ? eB.x : eA.x;        // per-half select
            float2 f = gin2[s * 32 + pairlane];
            float we = __int_as_float(half ? eB.y : eA.y);
            float w = ((idx0 + 2 * u + half) < cnt) ? we : 0.0f;
            accx += w * f.x;
            accy += w * f.y;
        }
    }

    // combine even-edge and odd-edge partial sums across half-waves
    accx += __shfl_xor(accx, 32);
    accy += __shfl_xor(accy, 32);

    float2 self = gin2[v * 32 + pairlane];
    float2 xv = ((const float2*)x)[v * 32 + pairlane];
    float2 res;
    res.x = sc * (accx + dv * dv * self.x) + tk * xv.x;
    res.y = sc * (accy + dv * dv * self.y) + tk * xv.y;
    if (half == 0) ((float2*)g_out)[v * 32 + pairlane] = res;  // 256 B per node
}

extern "C" void kernel_launch(void* const* d_in, const int* in_sizes, int n_in,
                              void* d_out, int out_size, void* d_ws, size_t ws_size,
                              hipStream_t stream) {
    const float* x    = (const float*)d_in[0];
    const float* temp = (const float*)d_in[1];
    const int*   ei   = (const int*)d_in[2];
    const int* src = ei;             // edge_index[0]
    const int* dst = ei + N_EDGES;   // edge_index[1]
    float* out = (float*)d_out;

    char* ws = (char*)d_ws;
    int*   counts    = (int*)  (ws + 0x000000);
    float* dinv      = (float*)(ws + 0x040000);
    int*   offsets   = (int*)  (ws + 0x080000);
    int*   blockSums = (int*)  (ws + 0x0C0000);
    int*   blockOffs = (int*)  (ws + 0x0C0400);
    int2*  csr       = (int2*) (ws + 0x1FFF00);   // ends 0x9FFF00
    char*  slack     =         (ws + 0x9FFF00);   // 256 B zeroed
    float* h0        = (float*)(ws + 0xA00000);
    float* h1        = (float*)(ws + 0x1A00000);
    int*   rank      = (int*)  h1;                // aliases h1, consumed pre-hop2

    hipMemsetAsync(counts, 0, N_NODES * sizeof(int), stream);
    hipMemsetAsync(slack, 0, 256, stream);

    count_deg<<<N_EDGES / 256, 256, 0, stream>>>(dst, counts, rank);
    compute_dinv<<<N_NODES / 256, 256, 0, stream>>>(counts, dinv);
    scan_pass1<<<256, 256, 0, stream>>>(counts, offsets, blockSums);
    scan_pass2<<<1, 256, 0, stream>>>(blockSums, blockOffs);
    scan_pass3<<<256, 256, 0, stream>>>(offsets, blockOffs);
    scatter_edges<<<N_EDGES / 256, 256, 0, stream>>>(src, dst, rank, offsets, dinv, csr);

    // Horner: p = temp[0]*x; for k=1..9: p = A_hat*p + temp[k]*x  (scale fused in hop1)
    const int hop_blocks = (N_NODES * D_FEAT) / 256;  // 1 wave per node
    const float* gin = x;
    float* bufs[2] = {h0, h1};
    for (int k = 1; k <= 9; ++k) {
        float* gout = (k == 9) ? out : bufs[(k - 1) & 1];
        hop_kernel<<<hop_blocks, 256, 0, stream>>>(gin, x, gout, temp,
                                                   offsets, counts, csr, dinv, k);
        gin = gout;
    }
}

// Round 5
// 475.176 us; speedup vs baseline: 2.3435x; 1.0944x over previous
//
#include <hip/hip_runtime.h>
#include <hip/hip_fp16.h>

#define N_NODES 65536
#define N_EDGES 1048576
#define D_FEAT  64

// ---------------- workspace layout (bytes) ----------------
// counts   : N int       @ 0x000000   (256 KB)
// dinv     : N float     @ 0x040000   (256 KB)
// offsets  : N int       @ 0x080000   (256 KB)
// blockSums: 256 int     @ 0x0C0000
// blockOffs: 256 int     @ 0x0C0400
// rank     : E int       @ 0x100000   (4 MB)
// csr      : E int2      @ 0x500000   (8 MB, ends 0xD00000)
// slack    : 256 B       @ 0xD00000   (zeroed; hop over-reads up to 15 records)
// xh       : N*64 half   @ 0xE00000   (8 MB)
// h0       : N*64 half   @ 0x1600000  (8 MB)
// h1       : N*64 half   @ 0x1E00000  (8 MB)  -- total ~38.75 MB

__global__ void count_deg(const int* __restrict__ dst, int* __restrict__ counts,
                          int* __restrict__ rank) {
    int e = blockIdx.x * blockDim.x + threadIdx.x;
    if (e < N_EDGES) rank[e] = atomicAdd(&counts[dst[e]], 1);
}

__global__ void compute_dinv(const int* __restrict__ counts, float* __restrict__ dinv) {
    int v = blockIdx.x * blockDim.x + threadIdx.x;
    if (v < N_NODES) dinv[v] = rsqrtf((float)(counts[v] + 1));  // +1 self-loop
}

__global__ void scan_pass1(const int* __restrict__ counts, int* __restrict__ offsets,
                           int* __restrict__ blockSums) {
    __shared__ int sdata[256];
    int tid = threadIdx.x;
    int gid = blockIdx.x * 256 + tid;
    int v = counts[gid];
    sdata[tid] = v;
    __syncthreads();
    for (int off = 1; off < 256; off <<= 1) {
        int t = (tid >= off) ? sdata[tid - off] : 0;
        __syncthreads();
        sdata[tid] += t;
        __syncthreads();
    }
    offsets[gid] = sdata[tid] - v;  // exclusive
    if (tid == 255) blockSums[blockIdx.x] = sdata[255];
}

__global__ void scan_pass2(int* __restrict__ blockSums, int* __restrict__ blockOffs) {
    __shared__ int sdata[256];
    int tid = threadIdx.x;
    int v = blockSums[tid];
    sdata[tid] = v;
    __syncthreads();
    for (int off = 1; off < 256; off <<= 1) {
        int t = (tid >= off) ? sdata[tid - off] : 0;
        __syncthreads();
        sdata[tid] += t;
        __syncthreads();
    }
    blockOffs[tid] = sdata[tid] - v;
}

__global__ void scan_pass3(int* __restrict__ offsets, const int* __restrict__ blockOffs) {
    int gid = blockIdx.x * 256 + threadIdx.x;
    offsets[gid] += blockOffs[blockIdx.x];
}

// No atomic: position = offsets[d] + rank[e] (rank recorded during count_deg)
__global__ void scatter_edges(const int* __restrict__ src, const int* __restrict__ dst,
                              const int* __restrict__ rank, const int* __restrict__ offsets,
                              const float* __restrict__ dinv, int2* __restrict__ csr) {
    int e = blockIdx.x * blockDim.x + threadIdx.x;
    if (e >= N_EDGES) return;
    int s = src[e];
    int d = dst[e];
    int pos = offsets[d] + rank[e];
    float w = dinv[s] * dinv[d];
    csr[pos] = make_int2(s, __float_as_int(w));
}

// x (fp32) -> xh (fp16), float4 -> 4 halves per thread
__global__ void cvt_x(const float* __restrict__ x, __half* __restrict__ xh) {
    int i = blockIdx.x * blockDim.x + threadIdx.x;
    float4 v = ((const float4*)x)[i];
    __half2 lo = __floats2half2_rn(v.x, v.y);
    __half2 hi = __floats2half2_rn(v.z, v.w);
    uint2 o;
    o.x = *(const unsigned int*)&lo;
    o.y = *(const unsigned int*)&hi;
    ((uint2*)xh)[i] = o;
}

// Horner hop: p_out = sc * (A_hat @ p_in) + temp[k] * x
// p stored fp16 (128 B rows -> half the L2-miss lines vs fp32; line rate is
// the ceiling). Quarter-wave gather: lane = 16*q + f; q = edge slot (4 edges
// per wave load-instruction), f = feature quad (features 4f..4f+3, uint2 = 4
// halves). Edge records on the scalar pipe (node id wave-uniform); per-lane
// edge select via 2-level cndmask; accumulate fp32; __shfl_xor(16/32) reduce.
// Additive x term and hop-1 self term use fp32 x. k==9 writes fp32 output.
__global__ void __launch_bounds__(256) hop_kernel(
        const __half* __restrict__ g_in, const float* __restrict__ x,
        __half* __restrict__ g_out, float* __restrict__ out_f32,
        const float* __restrict__ temp,
        const int* __restrict__ offsets, const int* __restrict__ counts,
        const int2* __restrict__ csr, const float* __restrict__ dinv, int k) {
    int gtid = blockIdx.x * blockDim.x + threadIdx.x;
    int v = __builtin_amdgcn_readfirstlane(gtid >> 6);  // node, wave-uniform
    int lane = gtid & 63;
    int q = lane >> 4;   // edge slot within group of 4
    int f = lane & 15;   // feature-quad index

    float dv = dinv[v];
    int start = offsets[v];
    int cnt = counts[v];
    float tk = temp[k];
    float sc = (k == 1) ? temp[0] : 1.0f;

    const uint2* gin2 = (const uint2*)g_in;  // 8 B = 4 fp16 features

    float a0 = 0.f, a1 = 0.f, a2 = 0.f, a3 = 0.f;

    int iters = (cnt + 15) >> 4;   // 16 edges per iteration
    for (int r = 0; r < iters; ++r) {
        int base = start + r * 16;
        #pragma unroll
        for (int g = 0; g < 4; ++g) {
            // 4 edge records, wave-uniform -> scalar loads
            int2 e0 = csr[base + 4 * g + 0];
            int2 e1 = csr[base + 4 * g + 1];
            int2 e2 = csr[base + 4 * g + 2];
            int2 e3 = csr[base + 4 * g + 3];
            // per-lane select by q
            int s01 = (q & 1) ? e1.x : e0.x;
            int s23 = (q & 1) ? e3.x : e2.x;
            int s   = (q & 2) ? s23 : s01;
            int w01 = (q & 1) ? e1.y : e0.y;
            int w23 = (q & 1) ? e3.y : e2.y;
            int wi  = (q & 2) ? w23 : w01;
            float w = ((r * 16 + 4 * g + q) < cnt) ? __int_as_float(wi) : 0.0f;
            uint2 hr = gin2[s * 16 + f];   // 16 lanes x 8 B = one 128 B row
            float2 lo = __half22float2(*(const __half2*)&hr.x);
            float2 hi = __half22float2(*(const __half2*)&hr.y);
            a0 += w * lo.x; a1 += w * lo.y; a2 += w * hi.x; a3 += w * hi.y;
        }
    }

    // reduce edge slots q=0..3
    a0 += __shfl_xor(a0, 16); a0 += __shfl_xor(a0, 32);
    a1 += __shfl_xor(a1, 16); a1 += __shfl_xor(a1, 32);
    a2 += __shfl_xor(a2, 16); a2 += __shfl_xor(a2, 32);
    a3 += __shfl_xor(a3, 16); a3 += __shfl_xor(a3, 32);

    float4 xv = ((const float4*)x)[v * 16 + f];
    float s0, s1, s2, s3;  // self row
    if (k == 1) {
        s0 = xv.x; s1 = xv.y; s2 = xv.z; s3 = xv.w;   // exact fp32 self for hop 1
    } else {
        uint2 hs = gin2[v * 16 + f];
        float2 lo = __half22float2(*(const __half2*)&hs.x);
        float2 hi = __half22float2(*(const __half2*)&hs.y);
        s0 = lo.x; s1 = lo.y; s2 = hi.x; s3 = hi.y;
    }
    float dd = dv * dv;
    float r0 = sc * (a0 + dd * s0) + tk * xv.x;
    float r1 = sc * (a1 + dd * s1) + tk * xv.y;
    float r2 = sc * (a2 + dd * s2) + tk * xv.z;
    float r3 = sc * (a3 + dd * s3) + tk * xv.w;

    if (q == 0) {
        if (k == 9) {
            ((float4*)out_f32)[v * 16 + f] = make_float4(r0, r1, r2, r3);
        } else {
            __half2 lo = __floats2half2_rn(r0, r1);
            __half2 hi = __floats2half2_rn(r2, r3);
            uint2 o;
            o.x = *(const unsigned int*)&lo;
            o.y = *(const unsigned int*)&hi;
            ((uint2*)g_out)[v * 16 + f] = o;
        }
    }
}

extern "C" void kernel_launch(void* const* d_in, const int* in_sizes, int n_in,
                              void* d_out, int out_size, void* d_ws, size_t ws_size,
                              hipStream_t stream) {
    const float* x    = (const float*)d_in[0];
    const float* temp = (const float*)d_in[1];
    const int*   ei   = (const int*)d_in[2];
    const int* src = ei;             // edge_index[0]
    const int* dst = ei + N_EDGES;   // edge_index[1]
    float* out = (float*)d_out;

    char* ws = (char*)d_ws;
    int*    counts    = (int*)   (ws + 0x000000);
    float*  dinv      = (float*) (ws + 0x040000);
    int*    offsets   = (int*)   (ws + 0x080000);
    int*    blockSums = (int*)   (ws + 0x0C0000);
    int*    blockOffs = (int*)   (ws + 0x0C0400);
    int*    rank      = (int*)   (ws + 0x100000);
    int2*   csr       = (int2*)  (ws + 0x500000);   // ends 0xD00000
    char*   slack     =          (ws + 0xD00000);   // 256 B zeroed
    __half* xh        = (__half*)(ws + 0xE00000);
    __half* h0        = (__half*)(ws + 0x1600000);
    __half* h1        = (__half*)(ws + 0x1E00000);

    hipMemsetAsync(counts, 0, N_NODES * sizeof(int), stream);
    hipMemsetAsync(slack, 0, 256, stream);

    count_deg<<<N_EDGES / 256, 256, 0, stream>>>(dst, counts, rank);
    compute_dinv<<<N_NODES / 256, 256, 0, stream>>>(counts, dinv);
    scan_pass1<<<256, 256, 0, stream>>>(counts, offsets, blockSums);
    scan_pass2<<<1, 256, 0, stream>>>(blockSums, blockOffs);
    scan_pass3<<<256, 256, 0, stream>>>(offsets, blockOffs);
    scatter_edges<<<N_EDGES / 256, 256, 0, stream>>>(src, dst, rank, offsets, dinv, csr);
    cvt_x<<<(N_NODES * D_FEAT / 4) / 256, 256, 0, stream>>>(x, xh);

    // Horner: p = temp[0]*x; for k=1..9: p = A_hat*p + temp[k]*x (scale fused in hop1)
    const int hop_blocks = (N_NODES * D_FEAT) / 256;  // 1 wave per node
    const __half* gin = xh;
    __half* bufs[2] = {h0, h1};
    for (int k = 1; k <= 9; ++k) {
        __half* gout = bufs[(k - 1) & 1];
        hop_kernel<<<hop_blocks, 256, 0, stream>>>(gin, x, gout, out, temp,
                                                   offsets, counts, csr, dinv, k);
        gin = gout;
    }
}